// Round 7
// baseline (246.608 us; speedup 1.0000x reference)
//
#include <hip/hip_runtime.h>

#define N_NODES 100000
#define N_EDGES 1600000
#define D_IN    256
#define D_OUT   128

typedef __attribute__((ext_vector_type(8))) short          bf16x8;
typedef __attribute__((ext_vector_type(8))) unsigned short ushort8;
typedef __attribute__((ext_vector_type(4))) unsigned short ushort4_t;
typedef __attribute__((ext_vector_type(4))) float          f32x4;

// f32 -> bf16 (round-to-nearest-even), as raw ushort
__device__ inline unsigned short f2bf(float f) {
  union { float f; unsigned u; } v; v.f = f;
  unsigned r = v.u + 0x7fffu + ((v.u >> 16) & 1u);
  return (unsigned short)(r >> 16);
}
__device__ inline float bf2f(unsigned short u) {
  union { unsigned u; float f; } v; v.u = ((unsigned)u) << 16;
  return v.f;
}

// ---------------------------------------------------------------------------
// Kernel 0: pack W[D_OUT][D_IN] f32 -> bf16 MFMA B-fragment order.
// Frag f = (n*8 + s)*64 + lane holds B[k = s*32+(lane>>4)*8 + j][col = n*16+(lane&15)]
//        = W[col][k], j = 0..7.  (Layout verified correct rounds 4-6.)
// ---------------------------------------------------------------------------
__global__ __launch_bounds__(256) void gcn_packW_kernel(
    const float* __restrict__ W, unsigned short* __restrict__ Wp) {
  int f = blockIdx.x * blockDim.x + threadIdx.x;   // 0..4095
  if (f >= 4096) return;
  int n = f >> 9, s = (f >> 6) & 7, lane = f & 63;
  int col = n * 16 + (lane & 15);
  int k0  = s * 32 + (lane >> 4) * 8;
#pragma unroll
  for (int j = 0; j < 8; ++j)
    Wp[f * 8 + j] = f2bf(W[col * D_IN + k0 + j]);
}

// ---------------------------------------------------------------------------
// Kernel 1: hT[8][N][16] (bf16) = transpose-chunked (bf16(x) @ W^T + b).
// 16 rows/wave (round-5 structure: more waves beat fatter waves — round-6
// post-mortem), but B-frags now come from LDS: the 64 KB W-pack is staged
// once per block, so the MFMA operand chain is ds_read_b128 (~12 cy) instead
// of ~300 cy L2 loads, and VMEM carries only the coalesced x stream.
// 512 threads = 8 waves = 128 rows/block; 64 KB LDS -> 2 blocks/CU.
// A layout: lane holds A[row=lane&15][k=(lane>>4)*8 + j].
// C layout: lane holds D[row=(lane>>4)*4 + i][col=lane&15].
// Epilogue writes hT[chunk=n][row][col&15] (transpose is free: stores were
// already scalar 2B).
// ---------------------------------------------------------------------------
__global__ __launch_bounds__(512) void gcn_linear_mfma_kernel(
    const float* __restrict__ x, const unsigned short* __restrict__ Wp,
    const float* __restrict__ b, unsigned short* __restrict__ hT) {
  __shared__ unsigned short lW[32768];   // 64 KiB, fragment-ordered
  const int tid  = threadIdx.x;
  const int lane = tid & 63;
  const int wid  = tid >> 6;             // 0..7
  const int r0   = blockIdx.x * 128 + wid * 16;

  // stage W-pack: 4096 x 16 B, 512 threads -> 8 iters, fully coalesced
#pragma unroll
  for (int i = 0; i < 8; ++i) {
    int idx = i * 512 + tid;
    *(ushort8*)(&lW[idx * 8]) = *(const ushort8*)(Wp + (size_t)idx * 8);
  }
  __syncthreads();

  int arow = r0 + (lane & 15);
  arow = arow < N_NODES ? arow : N_NODES - 1;      // clamp; OOB rows never stored
  const int kg = (lane >> 4) * 8;
  const float* xrow = x + (size_t)arow * D_IN + kg;

  f32x4 acc[8];
#pragma unroll
  for (int n = 0; n < 8; ++n) acc[n] = (f32x4){0.f, 0.f, 0.f, 0.f};

#pragma unroll
  for (int s = 0; s < 8; ++s) {
    float4 a0 = *(const float4*)(xrow + s * 32);
    float4 a1 = *(const float4*)(xrow + s * 32 + 4);
    bf16x8 af;
    af[0] = (short)f2bf(a0.x); af[1] = (short)f2bf(a0.y);
    af[2] = (short)f2bf(a0.z); af[3] = (short)f2bf(a0.w);
    af[4] = (short)f2bf(a1.x); af[5] = (short)f2bf(a1.y);
    af[6] = (short)f2bf(a1.z); af[7] = (short)f2bf(a1.w);
#pragma unroll
    for (int n = 0; n < 8; ++n) {
      bf16x8 bfrag = *(const bf16x8*)(&lW[(size_t)((n * 8 + s) * 64 + lane) * 8]);
      acc[n] = __builtin_amdgcn_mfma_f32_16x16x32_bf16(af, bfrag, acc[n], 0, 0, 0);
    }
  }

  // epilogue: + bias, bf16 store into chunked-transposed hT
  const int col0 = lane & 15;
  const int q4   = (lane >> 4) * 4;
#pragma unroll
  for (int n = 0; n < 8; ++n) {
    const float bias = b[n * 16 + col0];
    unsigned short* hc = hT + (size_t)n * N_NODES * 16;
#pragma unroll
    for (int i = 0; i < 4; ++i) {
      const int row = r0 + q4 + i;
      if (row < N_NODES)
        hc[(size_t)row * 16 + col0] = f2bf(acc[n][i] + bias);
    }
  }
}

// ---------------------------------------------------------------------------
// Kernel 2: row_ptr[v] = lower_bound(dst, v) over sorted dst (CSR offsets).
// ---------------------------------------------------------------------------
__global__ __launch_bounds__(256) void gcn_rowptr_kernel(
    const int* __restrict__ dst, int* __restrict__ row_ptr) {
  int v = blockIdx.x * blockDim.x + threadIdx.x;
  if (v > N_NODES) return;
  int lo = 0, hi = N_EDGES;
  while (lo < hi) {
    int mid = (lo + hi) >> 1;
    if (dst[mid] < v) lo = mid + 1; else hi = mid;
  }
  row_ptr[v] = lo;
}

// ---------------------------------------------------------------------------
// Kernel 3: d-chunked, XCD-pinned segment sum.
//   out[v][16c .. 16c+15] = sum_e hT[c][src[e]][:] * w[e]
// chunk c = blockIdx % 8: round-robin block->XCD dispatch pins all blocks of
// chunk c to XCD c, whose 4 MB L2 holds the whole 3.2 MB hT chunk -> the
// 410 MB of gather traffic moves from the L3 wall (~6 TB/s, round-6
// bottleneck) to per-XCD L2. One wave per (node, chunk): 16 edge slots x
// 4 lanes (8 B of the 32 B row each); shfl_xor(4,8,16,32) reduce; float4
// store by slot 0. Atomic-free, deterministic.
// ---------------------------------------------------------------------------
__global__ __launch_bounds__(256) void gcn_agg_kernel(
    const unsigned short* __restrict__ hT, const int* __restrict__ src,
    const float* __restrict__ w, const int* __restrict__ rp,
    float* __restrict__ out) {
  const int chunk = blockIdx.x & 7;
  const int node  = ((blockIdx.x >> 3) << 2) + (threadIdx.x >> 6);
  if (node >= N_NODES) return;
  const int lane = threadIdx.x & 63;
  const int slot = lane >> 2;        // edge slot 0..15
  const int q    = lane & 3;         // dim quarter within the 16-dim chunk
  const unsigned short* hc = hT + (size_t)chunk * N_NODES * 16;

  const int s = rp[node], e = rp[node + 1];
  float acc[4] = {0.f, 0.f, 0.f, 0.f};

  for (int base = s; base < e; base += 16) {
    const int  i = base + slot;
    const bool valid = (i < e);
    const int  ic = valid ? i : s;   // s is valid whenever the loop runs
    const int   sv = src[ic];
    const float wv = valid ? w[ic] : 0.f;
    ushort4_t hv = *(const ushort4_t*)(hc + (size_t)sv * 16 + (q << 2));
#pragma unroll
    for (int k = 0; k < 4; ++k) acc[k] += bf2f(hv[k]) * wv;
  }

#pragma unroll
  for (int k = 0; k < 4; ++k) {
    acc[k] += __shfl_xor(acc[k], 4);
    acc[k] += __shfl_xor(acc[k], 8);
    acc[k] += __shfl_xor(acc[k], 16);
    acc[k] += __shfl_xor(acc[k], 32);
  }

  if (slot == 0) {
    float4 o = {acc[0], acc[1], acc[2], acc[3]};
    *(float4*)(out + (size_t)node * D_OUT + chunk * 16 + (q << 2)) = o;
  }
}

extern "C" void kernel_launch(void* const* d_in, const int* in_sizes, int n_in,
                              void* d_out, int out_size, void* d_ws, size_t ws_size,
                              hipStream_t stream) {
  const float* x   = (const float*)d_in[0];
  const int*   src = (const int*)d_in[1];
  const int*   dst = (const int*)d_in[2];
  const float* w   = (const float*)d_in[3];
  const float* W   = (const float*)d_in[4];
  const float* b   = (const float*)d_in[5];
  float* out = (float*)d_out;

  // workspace: Wpack (64 KB) | hT bf16 [8][N][16] (25.6 MB) | row_ptr (400 KB)
  unsigned short* Wp = (unsigned short*)d_ws;
  unsigned short* hT = (unsigned short*)((char*)d_ws + 65536);
  int* row_ptr = (int*)((char*)d_ws + 65536 + (size_t)N_NODES * D_OUT * sizeof(unsigned short));

  // 0) pack W -> bf16 fragment order
  gcn_packW_kernel<<<16, 256, 0, stream>>>(W, Wp);
  // 1) hT = chunked-transposed bf16(x @ W^T + b), 128 rows/block
  gcn_linear_mfma_kernel<<<(N_NODES + 127) / 128, 512, 0, stream>>>(x, Wp, b, hT);
  // 2) CSR offsets from sorted dst
  gcn_rowptr_kernel<<<(N_NODES + 1 + 255) / 256, 256, 0, stream>>>(dst, row_ptr);
  // 3) XCD-pinned d-chunked segment-sum: 8 chunks x 25000 node-blocks
  gcn_agg_kernel<<<8 * (N_NODES / 4), 256, 0, stream>>>(hT, src, w, row_ptr, out);
}

// Round 8
// 110.748 us; speedup vs baseline: 2.2267x; 2.2267x over previous
//
#include <hip/hip_runtime.h>

#define N_NODES 100000
#define N_EDGES 1600000
#define D_IN    256
#define D_OUT   128

typedef __attribute__((ext_vector_type(8))) short          bf16x8;
typedef __attribute__((ext_vector_type(8))) unsigned short ushort8;
typedef __attribute__((ext_vector_type(4))) float          f32x4;

// f32 -> bf16 (round-to-nearest-even), as raw ushort
__device__ inline unsigned short f2bf(float f) {
  union { float f; unsigned u; } v; v.f = f;
  unsigned r = v.u + 0x7fffu + ((v.u >> 16) & 1u);
  return (unsigned short)(r >> 16);
}
__device__ inline float bf2f(unsigned short u) {
  union { unsigned u; float f; } v; v.u = ((unsigned)u) << 16;
  return v.f;
}

// ---------------------------------------------------------------------------
// Kernel 0: pack W[D_OUT][D_IN] f32 -> bf16 MFMA B-fragment order.
// Frag f = (n*8 + s)*64 + lane holds B[k = s*32+(lane>>4)*8 + j][col = n*16+(lane&15)]
//        = W[col][k], j = 0..7.  (Layout verified correct rounds 4-7.)
// ---------------------------------------------------------------------------
__global__ __launch_bounds__(256) void gcn_packW_kernel(
    const float* __restrict__ W, unsigned short* __restrict__ Wp) {
  int f = blockIdx.x * blockDim.x + threadIdx.x;   // 0..4095
  if (f >= 4096) return;
  int n = f >> 9, s = (f >> 6) & 7, lane = f & 63;
  int col = n * 16 + (lane & 15);
  int k0  = s * 32 + (lane >> 4) * 8;
#pragma unroll
  for (int j = 0; j < 8; ++j)
    Wp[f * 8 + j] = f2bf(W[col * D_IN + k0 + j]);
}

// ---------------------------------------------------------------------------
// Kernel 1: h[N][128] (bf16) = bf16(x) @ W^T + b via mfma_f32_16x16x32_bf16.
// 16 rows/wave (round-6 post-mortem: more waves beat fatter waves). B-frags
// come from LDS: the 64 KB W-pack is staged once per block, so the MFMA
// operand chain is ds_read_b128 (~12 cy) instead of ~300 cy L2 loads, and
// VMEM carries only the coalesced x stream (16 float4 in flight per wave).
// 512 threads = 8 waves = 128 rows/block; 64 KB LDS -> 2 blocks/CU.
// A layout: lane holds A[row=lane&15][k=(lane>>4)*8 + j].
// C layout: lane holds D[row=(lane>>4)*4 + i][col=lane&15].
// ---------------------------------------------------------------------------
__global__ __launch_bounds__(512) void gcn_linear_mfma_kernel(
    const float* __restrict__ x, const unsigned short* __restrict__ Wp,
    const float* __restrict__ b, unsigned short* __restrict__ h) {
  __shared__ unsigned short lW[32768];   // 64 KiB, fragment-ordered
  const int tid  = threadIdx.x;
  const int lane = tid & 63;
  const int wid  = tid >> 6;             // 0..7
  const int r0   = blockIdx.x * 128 + wid * 16;

  // stage W-pack: 4096 x 16 B, 512 threads -> 8 iters, fully coalesced
#pragma unroll
  for (int i = 0; i < 8; ++i) {
    int idx = i * 512 + tid;
    *(ushort8*)(&lW[idx * 8]) = *(const ushort8*)(Wp + (size_t)idx * 8);
  }
  __syncthreads();

  int arow = r0 + (lane & 15);
  arow = arow < N_NODES ? arow : N_NODES - 1;      // clamp; OOB rows never stored
  const int kg = (lane >> 4) * 8;
  const float* xrow = x + (size_t)arow * D_IN + kg;

  f32x4 acc[8];
#pragma unroll
  for (int n = 0; n < 8; ++n) acc[n] = (f32x4){0.f, 0.f, 0.f, 0.f};

#pragma unroll
  for (int s = 0; s < 8; ++s) {
    float4 a0 = *(const float4*)(xrow + s * 32);
    float4 a1 = *(const float4*)(xrow + s * 32 + 4);
    bf16x8 af;
    af[0] = (short)f2bf(a0.x); af[1] = (short)f2bf(a0.y);
    af[2] = (short)f2bf(a0.z); af[3] = (short)f2bf(a0.w);
    af[4] = (short)f2bf(a1.x); af[5] = (short)f2bf(a1.y);
    af[6] = (short)f2bf(a1.z); af[7] = (short)f2bf(a1.w);
#pragma unroll
    for (int n = 0; n < 8; ++n) {
      bf16x8 bfrag = *(const bf16x8*)(&lW[(size_t)((n * 8 + s) * 64 + lane) * 8]);
      acc[n] = __builtin_amdgcn_mfma_f32_16x16x32_bf16(af, bfrag, acc[n], 0, 0, 0);
    }
  }

  // epilogue: + bias, bf16 store (scalar 2B stores, 16-lane col groups
  // coalesce to 32B segments; WRITE_SIZE confirmed efficient in rounds 4-6)
  const int col0 = lane & 15;
  const int q4   = (lane >> 4) * 4;
#pragma unroll
  for (int n = 0; n < 8; ++n) {
    const int col = n * 16 + col0;
    const float bias = b[col];
#pragma unroll
    for (int i = 0; i < 4; ++i) {
      const int row = r0 + q4 + i;
      if (row < N_NODES)
        h[(size_t)row * D_OUT + col] = f2bf(acc[n][i] + bias);
    }
  }
}

// ---------------------------------------------------------------------------
// Kernel 2: row_ptr[v] = lower_bound(dst, v) over sorted dst (CSR offsets).
// ---------------------------------------------------------------------------
__global__ __launch_bounds__(256) void gcn_rowptr_kernel(
    const int* __restrict__ dst, int* __restrict__ row_ptr) {
  int v = blockIdx.x * blockDim.x + threadIdx.x;
  if (v > N_NODES) return;
  int lo = 0, hi = N_EDGES;
  while (lo < hi) {
    int mid = (lo + hi) >> 1;
    if (dst[mid] < v) lo = mid + 1; else hi = mid;
  }
  row_ptr[v] = lo;
}

// ---------------------------------------------------------------------------
// Kernel 3 (round-6 structure, the measured optimum): one WAVE per node,
// 4 lane-groups x 16 lanes, 4 edges per group per iteration (16 edges/wave
// = mean degree). Per-edge gather is the FULL 256 B row (16 lanes x 16 B,
// 4 complete cache lines -> no fill-granularity waste; round-7 lesson).
// shfl_xor(16,32) cross-group reduce, float4 store. Atomic-free.
// Gather path is BW-walled at ~6 TB/s mixed L3/HBM: 410 MB -> ~66 us floor.
// ---------------------------------------------------------------------------
__global__ __launch_bounds__(256) void gcn_agg_kernel(
    const unsigned short* __restrict__ h, const int* __restrict__ src,
    const float* __restrict__ w, const int* __restrict__ rp,
    float* __restrict__ out) {
  const int node = (blockIdx.x << 2) + (threadIdx.x >> 6);
  if (node >= N_NODES) return;
  const int lane = threadIdx.x & 63;
  const int g  = lane >> 4;          // group 0..3
  const int dg = (lane & 15) << 3;   // dim offset 0,8,...,120

  const int s = rp[node], e = rp[node + 1];
  float acc[8];
#pragma unroll
  for (int j = 0; j < 8; ++j) acc[j] = 0.f;

  for (int base = s; base < e; base += 16) {
    const int i0 = base + (g << 2);      // group-uniform
    if (i0 < e) {
      int   sv[4];
      float wv[4];
#pragma unroll
      for (int j = 0; j < 4; ++j) {
        int  i = i0 + j;
        bool valid = (i < e);
        int  ic = valid ? i : i0;        // i0 is valid here
        sv[j] = src[ic];
        wv[j] = valid ? w[ic] : 0.f;
      }
      ushort8 hv[4];
#pragma unroll
      for (int j = 0; j < 4; ++j)
        hv[j] = *(const ushort8*)(h + (size_t)sv[j] * D_OUT + dg);
#pragma unroll
      for (int j = 0; j < 4; ++j)
#pragma unroll
        for (int k = 0; k < 8; ++k)
          acc[k] += bf2f(hv[j][k]) * wv[j];
    }
  }

#pragma unroll
  for (int j = 0; j < 8; ++j) acc[j] += __shfl_xor(acc[j], 16);
#pragma unroll
  for (int j = 0; j < 8; ++j) acc[j] += __shfl_xor(acc[j], 32);

  if (g == 0) {
    float4 o0 = {acc[0], acc[1], acc[2], acc[3]};
    float4 o1 = {acc[4], acc[5], acc[6], acc[7]};
    float* op = out + (size_t)node * D_OUT + dg;
    *(float4*)(op)     = o0;
    *(float4*)(op + 4) = o1;
  }
}

extern "C" void kernel_launch(void* const* d_in, const int* in_sizes, int n_in,
                              void* d_out, int out_size, void* d_ws, size_t ws_size,
                              hipStream_t stream) {
  const float* x   = (const float*)d_in[0];
  const int*   src = (const int*)d_in[1];
  const int*   dst = (const int*)d_in[2];
  const float* w   = (const float*)d_in[3];
  const float* W   = (const float*)d_in[4];
  const float* b   = (const float*)d_in[5];
  float* out = (float*)d_out;

  // workspace: Wpack (64 KB) | h bf16 [N][128] (25.6 MB) | row_ptr (400 KB)
  unsigned short* Wp = (unsigned short*)d_ws;
  unsigned short* h  = (unsigned short*)((char*)d_ws + 65536);
  int* row_ptr = (int*)((char*)d_ws + 65536 + (size_t)N_NODES * D_OUT * sizeof(unsigned short));

  // 0) pack W -> bf16 fragment order
  gcn_packW_kernel<<<16, 256, 0, stream>>>(W, Wp);
  // 1) CSR offsets (independent of h -> launch before the big GEMM)
  gcn_rowptr_kernel<<<(N_NODES + 1 + 255) / 256, 256, 0, stream>>>(dst, row_ptr);
  // 2) h = bf16(x @ W^T + b), 128 rows/block, LDS-staged W
  gcn_linear_mfma_kernel<<<(N_NODES + 127) / 128, 512, 0, stream>>>(x, Wp, b, h);
  // 3) segment-sum of w-scaled gathered rows
  gcn_agg_kernel<<<N_NODES / 4, 256, 0, stream>>>(h, src, w, row_ptr, out);
}